// Round 16
// baseline (67.846 us; speedup 1.0000x reference)
//
#include <hip/hip_runtime.h>

// MoE block: B=128,K=32 -> N=4096 tokens, D=1024, H=256, E=32, top-1 routing.
// out[tok] = relu(relu(x[tok] @ W1[e] + b1[e]) @ W2[e] + b2[e]), e = argmax(x@rw.T+rb)
// 5 launches (no memset; R15's queued/spin design timed out -> reverted to the
// proven R14 frame): prep (rw hi/lo split + zero counts), router (bf16 rw, writes
// xb + histogram), scan_scatter (prefix/slots/scatter), expert_gemm<L1 from xb>,
// expert_gemm<L2>. GEMM bodies are R14-proven: in-LDS transpose of fp32 weights,
// swizzled LDS at bank floor, depth-2 register prefetch.

#define N_TOK 4096
#define DDIM  1024
#define HDIM  256
#define NEXP  32
#define TPX   136          // max 32-token tiles per XCD class (<=132 worst case)

typedef __attribute__((ext_vector_type(8))) short bf16x8;   // 8 bf16 in 4 VGPRs
typedef __attribute__((ext_vector_type(4))) float f32x4;

__device__ __forceinline__ unsigned short f2bf(float f) {   // RNE f32->bf16
  union { float f; unsigned u; } v; v.f = f;
  unsigned r = v.u + 0x7FFFu + ((v.u >> 16) & 1u);
  return (unsigned short)(r >> 16);
}
__device__ __forceinline__ float bf2f(unsigned short h) {
  union { unsigned u; float f; } v; v.u = ((unsigned)h) << 16;
  return v.f;
}
// LDS tile addressing: row-major stride 72 shorts, kk bits 3-5 XORed with (row>>3)&7.
// b128 frag reads ~floor; b64 A-writes floor; b128 B-writes exact floor.
__device__ __forceinline__ int swz(int row, int kk) {
  return row * 72 + (kk ^ (((row >> 3) & 7) << 3));
}

// ---------------- K0: prep -- rw hi/lo bf16 split + zero counts (R1-proven) ----------
__global__ __launch_bounds__(256) void prep_kernel(const float* __restrict__ rw,
    unsigned short* __restrict__ rwhi, unsigned short* __restrict__ rwlo,
    int* __restrict__ counts) {
  if (blockIdx.x == 0 && threadIdx.x < NEXP) counts[threadIdx.x] = 0;
  int i = blockIdx.x * 256 + threadIdx.x;   // 32*1024 elements, grid=128
  float w = rw[i];
  unsigned short h = f2bf(w);
  rwhi[i] = h;
  rwlo[i] = f2bf(w - bf2f(h));
}

// ---------------- K1: router (fp32-accurate logits via 4-term bf16 split MFMA) --------
// 256 thr = 4 waves per 16-token tile; wave w owns K window [w*256,+256).
// Weights pre-split (prep) -> no weight cvt in the hot loop; writes xb (bf16 x,
// same RNE rounding as the old in-GEMM cvt -> numerics unchanged) and histogram.
__global__ __launch_bounds__(256) void router_kernel(
    const float* __restrict__ x, const unsigned short* __restrict__ rwhi,
    const unsigned short* __restrict__ rwlo, const float* __restrict__ rb,
    unsigned short* __restrict__ xb, int* __restrict__ routed,
    int* __restrict__ counts) {
  __shared__ float red[4][64][8];
  int b = blockIdx.x;
  int t = threadIdx.x, w = t >> 6, l = t & 63;
  int m = l & 15, kb = l >> 4;
  int tok = b * 16 + m;
  int kbase = w * 256;
  const float* xrow = x + (size_t)tok * DDIM + kbase + kb * 8;
  unsigned short* xbrow = xb + (size_t)tok * DDIM + kbase + kb * 8;
  const unsigned short* w0h = rwhi + (size_t)m * DDIM + kbase + kb * 8;
  const unsigned short* w0l = rwlo + (size_t)m * DDIM + kbase + kb * 8;
  const unsigned short* w1h = rwhi + (size_t)(16 + m) * DDIM + kbase + kb * 8;
  const unsigned short* w1l = rwlo + (size_t)(16 + m) * DDIM + kbase + kb * 8;
  f32x4 acc0 = {0.f,0.f,0.f,0.f}, acc1 = {0.f,0.f,0.f,0.f};
#pragma unroll
  for (int q = 0; q < 8; q++) {
    float4 xa = *(const float4*)(xrow + q * 32);
    float4 xc = *(const float4*)(xrow + q * 32 + 4);
    float xv[8] = {xa.x, xa.y, xa.z, xa.w, xc.x, xc.y, xc.z, xc.w};
    bf16x8 xhi, xlo;
#pragma unroll
    for (int i = 0; i < 8; i++) {
      unsigned short hh = f2bf(xv[i]);
      xhi[i] = (short)hh;
      xlo[i] = (short)f2bf(xv[i] - bf2f(hh));
    }
    *(bf16x8*)(xbrow + q * 32) = xhi;   // xb written exactly once per (tok,k)
    bf16x8 wh0 = *(const bf16x8*)(w0h + q * 32);
    bf16x8 wl0 = *(const bf16x8*)(w0l + q * 32);
    bf16x8 wh1 = *(const bf16x8*)(w1h + q * 32);
    bf16x8 wl1 = *(const bf16x8*)(w1l + q * 32);
    acc0 = __builtin_amdgcn_mfma_f32_16x16x32_bf16(xhi, wh0, acc0, 0, 0, 0);
    acc0 = __builtin_amdgcn_mfma_f32_16x16x32_bf16(xlo, wh0, acc0, 0, 0, 0);
    acc0 = __builtin_amdgcn_mfma_f32_16x16x32_bf16(xhi, wl0, acc0, 0, 0, 0);
    acc1 = __builtin_amdgcn_mfma_f32_16x16x32_bf16(xhi, wh1, acc1, 0, 0, 0);
    acc1 = __builtin_amdgcn_mfma_f32_16x16x32_bf16(xlo, wh1, acc1, 0, 0, 0);
    acc1 = __builtin_amdgcn_mfma_f32_16x16x32_bf16(xhi, wl1, acc1, 0, 0, 0);
    acc0 = __builtin_amdgcn_mfma_f32_16x16x32_bf16(xlo, wl0, acc0, 0, 0, 0);
    acc1 = __builtin_amdgcn_mfma_f32_16x16x32_bf16(xlo, wl1, acc1, 0, 0, 0);
  }
  *(f32x4*)&red[w][l][0] = acc0;
  *(f32x4*)&red[w][l][4] = acc1;
  __syncthreads();
  if (w == 0) {
    f32x4 s0 = {0.f,0.f,0.f,0.f}, s1 = {0.f,0.f,0.f,0.f};
#pragma unroll
    for (int ww = 0; ww < 4; ww++) {
      s0 += *(const f32x4*)&red[ww][l][0];
      s1 += *(const f32x4*)&red[ww][l][4];
    }
    float rb0 = rb[m], rb1 = rb[16 + m];
#pragma unroll
    for (int r = 0; r < 4; r++) {       // token row = kb*4+r
      float v0 = s0[r] + rb0;
      float v1 = s1[r] + rb1;
      float val = v0; int idx = m;
      if (v1 > v0) { val = v1; idx = 16 + m; }   // ties -> smaller e (np.argmax)
#pragma unroll
      for (int s = 1; s < 16; s <<= 1) {
        float ov = __shfl_xor(val, s);
        int oi = __shfl_xor(idx, s);
        if (ov > val || (ov == val && oi < idx)) { val = ov; idx = oi; }
      }
      if (m == 0) {
        routed[b * 16 + kb * 4 + r] = idx;
        atomicAdd(&counts[idx], 1);     // histogram here (R1-proven) -> scan skips it
      }
    }
  }
}

// ---------------- K2: prefix + XCD-pinned tile slots + scatter ----------------------
// meta[0..7] = tiles per XCD class; meta[8 + cls + 8*rank] = (e<<24)|(nrow<<16)|start.
// All tiles of expert e sit at consecutive ranks of class e&7 (L2 temporal locality).
__global__ __launch_bounds__(512) void scan_scatter_kernel(const int* __restrict__ routed,
    const int* __restrict__ counts, int* __restrict__ meta, int* __restrict__ order) {
  __shared__ int scur[NEXP];
  int t = threadIdx.x;
  if (t < NEXP) {                           // lanes 0..31 of wave 0
    int c = counts[t];
    int nt = (c + 31) >> 5;                 // 32-token tiles
    int ic = c;
#pragma unroll
    for (int s = 1; s < NEXP; s <<= 1) {
      int pc = __shfl_up(ic, s);
      if (t >= s) ic += pc;
    }
    int off = ic - c;
    scur[t] = off;
    int cls = t & 7, pos = t >> 3;          // XCD class, rank-in-class position
    int rank = 0;
#pragma unroll
    for (int j = 0; j < 4; j++) {
      int v = __shfl(nt, cls + j * 8);
      if (pos > j) rank += v;
    }
    for (int s2 = 0; s2 < nt; s2++) {
      int nr = c - s2 * 32; if (nr > 32) nr = 32;
      meta[8 + cls + 8 * (rank + s2)] = (t << 24) | (nr << 16) | (off + s2 * 32);
    }
    if (pos == 3) meta[cls] = rank + nt;    // per-class tile count
  }
  __syncthreads();
  for (int n = t; n < N_TOK; n += 512) {
    int e = routed[n];
    int p = atomicAdd(&scur[e], 1);         // intra-expert order arbitrary: out invariant
    order[p] = n;
  }
}

// ---------------- K3/K4: grouped GEMM with in-LDS transpose of fp32 weights ----------
// Tile 32 tok x 64 cols, 256 thr = 4 waves (wave w owns 16 cols). Per 64-k chunk:
// stage A (gathered rows; bf16 source for both layers now; 2 passes, 16 thr/row,
// b64 writes at floor) and B (W[k][n] fp32 -> bf16 transposed, b128 ds_write at
// exact bank floor) into swizzled LDS. Depth-2 register prefetch; vmcnt stays in
// flight across the barrier. 1-D grid, y-OUTERMOST in rank order.
template <int KDIM, int NTOT, bool OUT_BF16>
__global__ __launch_bounds__(256) void expert_gemm_kernel(
    const unsigned short* __restrict__ a_src, const float* __restrict__ wsrc,
    const float* __restrict__ bias, const int* __restrict__ meta,
    const int* __restrict__ order, void* __restrict__ outp) {
  constexpr int NCH = KDIM / 64;
  constexpr int NSLAB = NTOT / 64;
  __shared__ unsigned short AT[2][32 * 72];   //  9.2 KB
  __shared__ unsigned short BT[2][64 * 72];   // 18.4 KB
  int bid = blockIdx.x, xcd = bid & 7, r = bid >> 3;
  int ntc = meta[xcd];
  if (r >= ntc * NSLAB) return;
  int y = r / ntc, rank = r - y * ntc;
  int info = meta[8 + xcd + 8 * rank];
  int e = info >> 24, nrow = (info >> 16) & 0xff, ts = info & 0xffff;
  int c0 = y * 64;
  int t = threadIdx.x, w = t >> 6, l = t & 63, m = l & 15, kb = l >> 4;
  int ak4 = (t & 15) * 4;
  int bcn = t & 63, bkg = t >> 6;             // bkg in 0..3
  int atrp[2];
  const unsigned short* aH[2];
#pragma unroll
  for (int pp = 0; pp < 2; pp++) {
    atrp[pp] = (t >> 4) + pp * 16;
    int atok = order[ts + (atrp[pp] < nrow ? atrp[pp] : nrow - 1)];  // clamp: masked
    aH[pp] = a_src + (size_t)atok * KDIM + ak4;
  }
  const float* bS = wsrc + (size_t)e * KDIM * NTOT + c0 + bcn;

  ushort4 nAh[2][2];
  float nB[2][2][8];                          // all indices compile-time (full unroll)
  auto LOADC = [&](int c, int rbuf) {
#pragma unroll
    for (int pp = 0; pp < 2; pp++)
      nAh[rbuf][pp] = *(const ushort4*)(aH[pp] + c * 64);
#pragma unroll
    for (int u = 0; u < 2; u++)
#pragma unroll
      for (int j = 0; j < 8; j++)
        nB[rbuf][u][j] = bS[(size_t)(c * 64 + (bkg + 4 * u) * 8 + j) * NTOT];
  };

  f32x4 acc0 = {0.f,0.f,0.f,0.f}, acc1 = {0.f,0.f,0.f,0.f};
  LOADC(0, 0);
  LOADC(1, 1);
#pragma unroll
  for (int c = 0; c < NCH; c++) {
    const int p = c & 1;
#pragma unroll
    for (int pp = 0; pp < 2; pp++)            // A writes b64: floor (pure copy now)
      *(ushort4*)&AT[p][swz(atrp[pp], ak4)] = nAh[p][pp];
#pragma unroll
    for (int u = 0; u < 2; u++) {             // B writes b128: exact bank floor
      bf16x8 pv;
#pragma unroll
      for (int j = 0; j < 8; j++) pv[j] = (short)f2bf(nB[p][u][j]);
      *(bf16x8*)&BT[p][swz(bcn, (bkg + 4 * u) * 8)] = pv;
    }
    if (c + 2 < NCH) LOADC(c + 2, p);         // WAR-safe: ds_writes read regs at issue
    asm volatile("s_waitcnt lgkmcnt(0)" ::: "memory");   // LDS writes visible
    __builtin_amdgcn_s_barrier();                        // vmcnt stays in flight
#pragma unroll
    for (int ks = 0; ks < 2; ks++) {
      int kk = ks * 32 + kb * 8;
      bf16x8 bfr = *(const bf16x8*)&BT[p][swz(w * 16 + m, kk)];
      bf16x8 a0  = *(const bf16x8*)&AT[p][swz(m, kk)];
      bf16x8 a1  = *(const bf16x8*)&AT[p][swz(16 + m, kk)];
      acc0 = __builtin_amdgcn_mfma_f32_16x16x32_bf16(a0, bfr, acc0, 0, 0, 0);
      acc1 = __builtin_amdgcn_mfma_f32_16x16x32_bf16(a1, bfr, acc1, 0, 0, 0);
    }
    // reads of buf p retire before next chunk's lgkmcnt(0)+barrier; buf p is
    // rewritten only at c+2 (after that barrier) -> single barrier per chunk safe.
  }
  int col = c0 + w * 16 + m;
  float bz = bias[e * NTOT + col];
#pragma unroll
  for (int r2 = 0; r2 < 4; r2++) {            // C/D: col=lane&15, row=kb*4+r (+16)
    int r0 = kb * 4 + r2;
    if (r0 < nrow) {
      int tok = order[ts + r0];
      float v = acc0[r2] + bz; v = v > 0.f ? v : 0.f;
      if constexpr (OUT_BF16)
        ((unsigned short*)outp)[(size_t)tok * NTOT + col] = f2bf(v);
      else
        ((float*)outp)[(size_t)tok * NTOT + col] = v;
    }
    int r1 = 16 + kb * 4 + r2;
    if (r1 < nrow) {
      int tok = order[ts + r1];
      float v = acc1[r2] + bz; v = v > 0.f ? v : 0.f;
      if constexpr (OUT_BF16)
        ((unsigned short*)outp)[(size_t)tok * NTOT + col] = f2bf(v);
      else
        ((float*)outp)[(size_t)tok * NTOT + col] = v;
    }
  }
}

// ---------------- launch ----------------

extern "C" void kernel_launch(void* const* d_in, const int* in_sizes, int n_in,
                              void* d_out, int out_size, void* d_ws, size_t ws_size,
                              hipStream_t stream) {
  const float* x  = (const float*)d_in[0];
  const float* rw = (const float*)d_in[1];
  const float* rb = (const float*)d_in[2];
  const float* w1 = (const float*)d_in[3];
  const float* b1 = (const float*)d_in[4];
  const float* w2 = (const float*)d_in[5];
  const float* b2 = (const float*)d_in[6];
  float* out = (float*)d_out;

  char* ws = (char*)d_ws;
  unsigned short* xb   = (unsigned short*)(ws + 0);         //  8,388,608  x bf16 [N][D]
  unsigned short* hb   = (unsigned short*)(ws + 8388608);   //  2,097,152  h bf16 [N][H]
  unsigned short* rwhi = (unsigned short*)(ws + 10485760);  //     65,536
  unsigned short* rwlo = (unsigned short*)(ws + 10551296);  //     65,536
  int* routed = (int*)(ws + 10616832);                      //     16,384
  int* order  = (int*)(ws + 10633216);                      //     16,384
  int* counts = (int*)(ws + 10649600);                      //        128
  int* meta   = (int*)(ws + 10649728);                      //      4,608

  prep_kernel<<<dim3(128), dim3(256), 0, stream>>>(rw, rwhi, rwlo, counts);
  router_kernel<<<dim3(256), dim3(256), 0, stream>>>(
      x, rwhi, rwlo, rb, xb, routed, counts);
  scan_scatter_kernel<<<dim3(1), dim3(512), 0, stream>>>(routed, counts, meta, order);
  expert_gemm_kernel<DDIM, HDIM, true>
      <<<dim3(8 * TPX * (HDIM / 64)), dim3(256), 0, stream>>>(
      xb, w1, b1, meta, order, hb);
  expert_gemm_kernel<HDIM, DDIM, false>
      <<<dim3(8 * TPX * (DDIM / 64)), dim3(256), 0, stream>>>(
      hb, w2, b2, meta, order, out);
}

// Round 17
// 51.962 us; speedup vs baseline: 1.3057x; 1.3057x over previous
//
#include <hip/hip_runtime.h>

// MoE block: B=128,K=32 -> N=4096 tokens, D=1024, H=256, E=32, top-1 routing.
// out[tok] = relu(relu(x[tok] @ W1[e] + b1[e]) @ W2[e] + b2[e]), e = argmax(x@rw.T+rb)
// 4 launches (no tiny memset): router (256thr, 2 blocks/CU), scan_scatter,
// expert_gemm<L1> (32x64 tiles, 256thr), expert_gemm<L2> (32x64 tiles, 256thr).
// Weights consumed in ORIGINAL fp32 [K][N] layout; transpose+bf16-cvt during LDS
// staging; depth-2 register prefetch; swizzled LDS at bank floor. All tiles
// XCD-pinned by expert class with y-outermost slab order.
// [R16 lesson: prep/xb front-end regressed 15us (uncoalesced xb stores at low TLP
//  + extra latency-bound dispatch) -> this is the proven-best R14 artifact.]

#define N_TOK 4096
#define DDIM  1024
#define HDIM  256
#define NEXP  32
#define TPX   136          // max 32-token tiles per XCD class (<=132 worst case)

typedef __attribute__((ext_vector_type(8))) short bf16x8;   // 8 bf16 in 4 VGPRs
typedef __attribute__((ext_vector_type(4))) float f32x4;

__device__ __forceinline__ unsigned short f2bf(float f) {   // RNE f32->bf16
  union { float f; unsigned u; } v; v.f = f;
  unsigned r = v.u + 0x7FFFu + ((v.u >> 16) & 1u);
  return (unsigned short)(r >> 16);
}
__device__ __forceinline__ float bf2f(unsigned short h) {
  union { unsigned u; float f; } v; v.u = ((unsigned)h) << 16;
  return v.f;
}
// LDS tile addressing: row-major stride 72 shorts, kk bits 3-5 XORed with (row>>3)&7.
// b128 frag reads ~floor; b64 A-writes floor; b128 B-writes exact floor.
__device__ __forceinline__ int swz(int row, int kk) {
  return row * 72 + (kk ^ (((row >> 3) & 7) << 3));
}

// ---------------- K1: router (fp32-accurate logits via 4-term bf16 split MFMA) --------
// 256 thr = 4 waves per 16-token tile (2 blocks/CU); wave w owns K window [w*256,+256),
// rw loads inlined (rw is L2-resident).
__global__ __launch_bounds__(256) void router_kernel(
    const float* __restrict__ x, const float* __restrict__ rw,
    const float* __restrict__ rb, int* __restrict__ routed) {
  __shared__ float red[4][64][8];
  int b = blockIdx.x;
  int t = threadIdx.x, w = t >> 6, l = t & 63;
  int m = l & 15, kb = l >> 4;
  int tok = b * 16 + m;
  int kbase = w * 256;
  const float* xrow = x + (size_t)tok * DDIM + kbase + kb * 8;
  const float* w0p  = rw + (size_t)m * DDIM + kbase + kb * 8;
  const float* w1p  = rw + (size_t)(16 + m) * DDIM + kbase + kb * 8;
  f32x4 acc0 = {0.f,0.f,0.f,0.f}, acc1 = {0.f,0.f,0.f,0.f};
#pragma unroll
  for (int q = 0; q < 8; q++) {
    float4 xa = *(const float4*)(xrow + q * 32);
    float4 xc = *(const float4*)(xrow + q * 32 + 4);
    float4 wa0 = *(const float4*)(w0p + q * 32);
    float4 wc0 = *(const float4*)(w0p + q * 32 + 4);
    float4 wa1 = *(const float4*)(w1p + q * 32);
    float4 wc1 = *(const float4*)(w1p + q * 32 + 4);
    float xv[8]  = {xa.x, xa.y, xa.z, xa.w, xc.x, xc.y, xc.z, xc.w};
    float wv0[8] = {wa0.x, wa0.y, wa0.z, wa0.w, wc0.x, wc0.y, wc0.z, wc0.w};
    float wv1[8] = {wa1.x, wa1.y, wa1.z, wa1.w, wc1.x, wc1.y, wc1.z, wc1.w};
    bf16x8 xhi, xlo, h0, l0, h1, l1;
#pragma unroll
    for (int i = 0; i < 8; i++) {
      unsigned short hh;
      hh = f2bf(xv[i]);  xhi[i] = (short)hh; xlo[i] = (short)f2bf(xv[i]  - bf2f(hh));
      hh = f2bf(wv0[i]); h0[i]  = (short)hh; l0[i]  = (short)f2bf(wv0[i] - bf2f(hh));
      hh = f2bf(wv1[i]); h1[i]  = (short)hh; l1[i]  = (short)f2bf(wv1[i] - bf2f(hh));
    }
    acc0 = __builtin_amdgcn_mfma_f32_16x16x32_bf16(xhi, h0, acc0, 0, 0, 0);
    acc0 = __builtin_amdgcn_mfma_f32_16x16x32_bf16(xlo, h0, acc0, 0, 0, 0);
    acc0 = __builtin_amdgcn_mfma_f32_16x16x32_bf16(xhi, l0, acc0, 0, 0, 0);
    acc0 = __builtin_amdgcn_mfma_f32_16x16x32_bf16(xlo, l0, acc0, 0, 0, 0);
    acc1 = __builtin_amdgcn_mfma_f32_16x16x32_bf16(xhi, h1, acc1, 0, 0, 0);
    acc1 = __builtin_amdgcn_mfma_f32_16x16x32_bf16(xlo, h1, acc1, 0, 0, 0);
    acc1 = __builtin_amdgcn_mfma_f32_16x16x32_bf16(xhi, l1, acc1, 0, 0, 0);
    acc1 = __builtin_amdgcn_mfma_f32_16x16x32_bf16(xlo, l1, acc1, 0, 0, 0);
  }
  *(f32x4*)&red[w][l][0] = acc0;
  *(f32x4*)&red[w][l][4] = acc1;
  __syncthreads();
  if (w == 0) {
    f32x4 s0 = {0.f,0.f,0.f,0.f}, s1 = {0.f,0.f,0.f,0.f};
#pragma unroll
    for (int ww = 0; ww < 4; ww++) {
      s0 += *(const f32x4*)&red[ww][l][0];
      s1 += *(const f32x4*)&red[ww][l][4];
    }
    float rb0 = rb[m], rb1 = rb[16 + m];
#pragma unroll
    for (int r = 0; r < 4; r++) {       // token row = kb*4+r
      float v0 = s0[r] + rb0;
      float v1 = s1[r] + rb1;
      float val = v0; int idx = m;
      if (v1 > v0) { val = v1; idx = 16 + m; }   // ties -> smaller e (np.argmax)
#pragma unroll
      for (int s = 1; s < 16; s <<= 1) {
        float ov = __shfl_xor(val, s);
        int oi = __shfl_xor(idx, s);
        if (ov > val || (ov == val && oi < idx)) { val = ov; idx = oi; }
      }
      if (m == 0) routed[b * 16 + kb * 4 + r] = idx;
    }
  }
}

// ---------------- K2: histogram + scan + XCD-pinned tile slots + scatter --------------
// meta[0..7] = tiles per XCD class; meta[8 + cls + 8*rank] = (e<<24)|(nrow<<16)|start.
// All tiles of expert e sit at consecutive ranks of class e&7 (L2 temporal locality).
__global__ __launch_bounds__(512) void scan_scatter_kernel(const int* __restrict__ routed,
    int* __restrict__ meta, int* __restrict__ order) {
  __shared__ int scnt[NEXP];
  __shared__ int scur[NEXP];
  int t = threadIdx.x;
  if (t < NEXP) scnt[t] = 0;
  __syncthreads();
  for (int n = t; n < N_TOK; n += 512) atomicAdd(&scnt[routed[n]], 1);
  __syncthreads();
  if (t < NEXP) {                           // lanes 0..31 of wave 0
    int c = scnt[t];
    int nt = (c + 31) >> 5;                 // 32-token tiles
    int ic = c;
#pragma unroll
    for (int s = 1; s < NEXP; s <<= 1) {
      int pc = __shfl_up(ic, s);
      if (t >= s) ic += pc;
    }
    int off = ic - c;
    scur[t] = off;
    int cls = t & 7, pos = t >> 3;          // XCD class, rank-in-class position
    int rank = 0;
#pragma unroll
    for (int j = 0; j < 4; j++) {
      int v = __shfl(nt, cls + j * 8);
      if (pos > j) rank += v;
    }
    for (int s2 = 0; s2 < nt; s2++) {
      int nr = c - s2 * 32; if (nr > 32) nr = 32;
      meta[8 + cls + 8 * (rank + s2)] = (t << 24) | (nr << 16) | (off + s2 * 32);
    }
    if (pos == 3) meta[cls] = rank + nt;    // per-class tile count
  }
  __syncthreads();
  for (int n = t; n < N_TOK; n += 512) {
    int e = routed[n];
    int p = atomicAdd(&scur[e], 1);         // intra-expert order arbitrary: out invariant
    order[p] = n;
  }
}

// ---------------- K3/K4: grouped GEMM with in-LDS transpose of fp32 weights ----------
// Tile 32 tok x COLS cols, THREADS = COLS*4 (4 or 8 waves, wave w owns 16 cols).
// Per 64-k chunk: stage A (gathered rows, fp32->bf16 for L1; NPASS passes of the
// proven 16-thr/row float4 pattern) and B (W[k][n] fp32 -> bf16 transposed, b128
// ds_write at exact bank floor) into swizzled LDS. Depth-2 register prefetch;
// vmcnt stays in flight across the barrier. 1-D grid, y-OUTERMOST in rank order.
template <int KDIM, int NTOT, int COLS, int THREADS, bool A_FP32, bool OUT_BF16>
__global__ __launch_bounds__(THREADS) void expert_gemm_kernel(
    const void* __restrict__ a_src, const float* __restrict__ wsrc,
    const float* __restrict__ bias, const int* __restrict__ meta,
    const int* __restrict__ order, void* __restrict__ outp) {
  constexpr int NCH = KDIM / 64;
  constexpr int NSLAB = NTOT / COLS;
  constexpr int NPASS = (32 * 16) / THREADS;  // A-staging passes: 512thr->1, 256thr->2
  __shared__ unsigned short AT[2][32 * 72];   //  9.2 KB
  __shared__ unsigned short BT[2][COLS * 72]; // 18.4 KB (64) / 36.9 KB (128)
  int bid = blockIdx.x, xcd = bid & 7, r = bid >> 3;
  int ntc = meta[xcd];
  if (r >= ntc * NSLAB) return;
  int y = r / ntc, rank = r - y * ntc;
  int info = meta[8 + xcd + 8 * rank];
  int e = info >> 24, nrow = (info >> 16) & 0xff, ts = info & 0xffff;
  int c0 = y * COLS;
  int t = threadIdx.x, w = t >> 6, l = t & 63, m = l & 15, kb = l >> 4;
  // staging roles: A = 32 rows x 64 kk (16 thr/row, float4/ushort4, NPASS passes);
  //                B = col bcn=t&(COLS-1), k-groups bkg=t/COLS and bkg+4 (8 k's each)
  int ak4 = (t & 15) * 4;
  int bcn = t & (COLS - 1), bkg = t / COLS;   // bkg in 0..3 for both shapes
  int atrp[NPASS];
  const float* aF[NPASS];
  const unsigned short* aH[NPASS];
#pragma unroll
  for (int pp = 0; pp < NPASS; pp++) {
    atrp[pp] = (t >> 4) + pp * (THREADS >> 4);
    int atok = order[ts + (atrp[pp] < nrow ? atrp[pp] : nrow - 1)];  // clamp: masked
    aF[pp] = (const float*)a_src + (size_t)atok * KDIM + ak4;
    aH[pp] = (const unsigned short*)a_src + (size_t)atok * KDIM + ak4;
  }
  const float* bS = wsrc + (size_t)e * KDIM * NTOT + c0 + bcn;

  float4 nAf[2][NPASS]; ushort4 nAh[2][NPASS];
  float nB[2][2][8];                          // all indices compile-time (full unroll)
  auto LOADC = [&](int c, int rbuf) {
#pragma unroll
    for (int pp = 0; pp < NPASS; pp++) {
      if constexpr (A_FP32) nAf[rbuf][pp] = *(const float4*)(aF[pp] + c * 64);
      else                  nAh[rbuf][pp] = *(const ushort4*)(aH[pp] + c * 64);
    }
#pragma unroll
    for (int u = 0; u < 2; u++)
#pragma unroll
      for (int j = 0; j < 8; j++)
        nB[rbuf][u][j] = bS[(size_t)(c * 64 + (bkg + 4 * u) * 8 + j) * NTOT];
  };

  f32x4 acc0 = {0.f,0.f,0.f,0.f}, acc1 = {0.f,0.f,0.f,0.f};
  LOADC(0, 0);
  LOADC(1, 1);
#pragma unroll
  for (int c = 0; c < NCH; c++) {
    const int p = c & 1;
#pragma unroll
    for (int pp = 0; pp < NPASS; pp++) {      // A writes b64: floor
      ushort4 av;
      if constexpr (A_FP32) {
        av.x = f2bf(nAf[p][pp].x); av.y = f2bf(nAf[p][pp].y);
        av.z = f2bf(nAf[p][pp].z); av.w = f2bf(nAf[p][pp].w);
      } else av = nAh[p][pp];
      *(ushort4*)&AT[p][swz(atrp[pp], ak4)] = av;
    }
#pragma unroll
    for (int u = 0; u < 2; u++) {             // B writes b128: exact bank floor
      bf16x8 pv;
#pragma unroll
      for (int j = 0; j < 8; j++) pv[j] = (short)f2bf(nB[p][u][j]);
      *(bf16x8*)&BT[p][swz(bcn, (bkg + 4 * u) * 8)] = pv;
    }
    if (c + 2 < NCH) LOADC(c + 2, p);         // WAR-safe: ds_writes read regs at issue
    asm volatile("s_waitcnt lgkmcnt(0)" ::: "memory");   // LDS writes visible
    __builtin_amdgcn_s_barrier();                        // vmcnt stays in flight
#pragma unroll
    for (int ks = 0; ks < 2; ks++) {
      int kk = ks * 32 + kb * 8;
      bf16x8 bfr = *(const bf16x8*)&BT[p][swz(w * 16 + m, kk)];
      bf16x8 a0  = *(const bf16x8*)&AT[p][swz(m, kk)];
      bf16x8 a1  = *(const bf16x8*)&AT[p][swz(16 + m, kk)];
      acc0 = __builtin_amdgcn_mfma_f32_16x16x32_bf16(a0, bfr, acc0, 0, 0, 0);
      acc1 = __builtin_amdgcn_mfma_f32_16x16x32_bf16(a1, bfr, acc1, 0, 0, 0);
    }
    // reads of buf p retire before next chunk's lgkmcnt(0)+barrier -> 1 barrier safe;
    // buf p is rewritten only at c+2, after that barrier.
  }
  int col = c0 + w * 16 + m;
  float bz = bias[e * NTOT + col];
#pragma unroll
  for (int r2 = 0; r2 < 4; r2++) {            // C/D: col=lane&15, row=kb*4+r (+16)
    int r0 = kb * 4 + r2;
    if (r0 < nrow) {
      int tok = order[ts + r0];
      float v = acc0[r2] + bz; v = v > 0.f ? v : 0.f;
      if constexpr (OUT_BF16)
        ((unsigned short*)outp)[(size_t)tok * NTOT + col] = f2bf(v);
      else
        ((float*)outp)[(size_t)tok * NTOT + col] = v;
    }
    int r1 = 16 + kb * 4 + r2;
    if (r1 < nrow) {
      int tok = order[ts + r1];
      float v = acc1[r2] + bz; v = v > 0.f ? v : 0.f;
      if constexpr (OUT_BF16)
        ((unsigned short*)outp)[(size_t)tok * NTOT + col] = f2bf(v);
      else
        ((float*)outp)[(size_t)tok * NTOT + col] = v;
    }
  }
}

// ---------------- launch ----------------

extern "C" void kernel_launch(void* const* d_in, const int* in_sizes, int n_in,
                              void* d_out, int out_size, void* d_ws, size_t ws_size,
                              hipStream_t stream) {
  const float* x  = (const float*)d_in[0];
  const float* rw = (const float*)d_in[1];
  const float* rb = (const float*)d_in[2];
  const float* w1 = (const float*)d_in[3];
  const float* b1 = (const float*)d_in[4];
  const float* w2 = (const float*)d_in[5];
  const float* b2 = (const float*)d_in[6];
  float* out = (float*)d_out;

  char* ws = (char*)d_ws;
  unsigned short* hb = (unsigned short*)(ws + 0);   // 2,097,152  h bf16 [N][H]
  int* routed = (int*)(ws + 2097152);               //    16,384
  int* order  = (int*)(ws + 2113536);               //    16,384
  int* meta   = (int*)(ws + 2129920);               //     4,608

  router_kernel<<<dim3(256), dim3(256), 0, stream>>>(x, rw, rb, routed);
  scan_scatter_kernel<<<dim3(1), dim3(512), 0, stream>>>(routed, meta, order);
  expert_gemm_kernel<DDIM, HDIM, 64, 256, true, true>
      <<<dim3(8 * TPX * (HDIM / 64)), dim3(256), 0, stream>>>(
      x, w1, b1, meta, order, hb);
  expert_gemm_kernel<HDIM, DDIM, 64, 256, false, false>
      <<<dim3(8 * TPX * (DDIM / 64)), dim3(256), 0, stream>>>(
      hb, w2, b2, meta, order, out);
}

// Round 18
// 50.743 us; speedup vs baseline: 1.3370x; 1.0240x over previous
//
#include <hip/hip_runtime.h>
#include <hip/hip_bf16.h>

// MoE block: B=128,K=32 -> N=4096 tokens, D=1024, H=256, E=32, top-1 routing.
// out[tok] = relu(relu(x[tok] @ W1[e] + b1[e]) @ W2[e] + b2[e]), e = argmax(x@rw.T+rb)
// 4 launches (no tiny memset): router (256thr, 2 blocks/CU), scan_scatter,
// expert_gemm<L1> (32x64 tiles, 256thr), expert_gemm<L2> (32x64 tiles, 256thr).
// Weights consumed in ORIGINAL fp32 [K][N] layout; transpose+bf16-cvt during LDS
// staging; depth-2 register prefetch; swizzled LDS at bank floor; XCD-pinned tiles.
// [R18 delta: f2bf = hardware cvt (__float2bfloat16, RNE; pairs fuse to
//  v_cvt_pk_bf16_f32) instead of 4-5 VALU insts of bit-manip RNE -- staging was
//  VALU-bound on conversion (~110 insts/chunk/thread, ~5x the MFMA cycles).]

#define N_TOK 4096
#define DDIM  1024
#define HDIM  256
#define NEXP  32
#define TPX   136          // max 32-token tiles per XCD class (<=132 worst case)

typedef __attribute__((ext_vector_type(8))) short bf16x8;   // 8 bf16 in 4 VGPRs
typedef __attribute__((ext_vector_type(4))) float f32x4;

__device__ __forceinline__ unsigned short f2bf(float f) {   // RNE f32->bf16 (HW cvt)
  __hip_bfloat16 b = __float2bfloat16(f);
  union { __hip_bfloat16 b; unsigned short u; } v;
  v.b = b;
  return v.u;
}
__device__ __forceinline__ float bf2f(unsigned short h) {
  union { unsigned u; float f; } v; v.u = ((unsigned)h) << 16;
  return v.f;
}
// LDS tile addressing: row-major stride 72 shorts, kk bits 3-5 XORed with (row>>3)&7.
// b128 frag reads ~floor; b64 A-writes floor; b128 B-writes exact floor.
__device__ __forceinline__ int swz(int row, int kk) {
  return row * 72 + (kk ^ (((row >> 3) & 7) << 3));
}

// ---------------- K1: router (fp32-accurate logits via 4-term bf16 split MFMA) --------
// 256 thr = 4 waves per 16-token tile (2 blocks/CU); wave w owns K window [w*256,+256),
// rw loads inlined (rw is L2-resident).
__global__ __launch_bounds__(256) void router_kernel(
    const float* __restrict__ x, const float* __restrict__ rw,
    const float* __restrict__ rb, int* __restrict__ routed) {
  __shared__ float red[4][64][8];
  int b = blockIdx.x;
  int t = threadIdx.x, w = t >> 6, l = t & 63;
  int m = l & 15, kb = l >> 4;
  int tok = b * 16 + m;
  int kbase = w * 256;
  const float* xrow = x + (size_t)tok * DDIM + kbase + kb * 8;
  const float* w0p  = rw + (size_t)m * DDIM + kbase + kb * 8;
  const float* w1p  = rw + (size_t)(16 + m) * DDIM + kbase + kb * 8;
  f32x4 acc0 = {0.f,0.f,0.f,0.f}, acc1 = {0.f,0.f,0.f,0.f};
#pragma unroll
  for (int q = 0; q < 8; q++) {
    float4 xa = *(const float4*)(xrow + q * 32);
    float4 xc = *(const float4*)(xrow + q * 32 + 4);
    float4 wa0 = *(const float4*)(w0p + q * 32);
    float4 wc0 = *(const float4*)(w0p + q * 32 + 4);
    float4 wa1 = *(const float4*)(w1p + q * 32);
    float4 wc1 = *(const float4*)(w1p + q * 32 + 4);
    float xv[8]  = {xa.x, xa.y, xa.z, xa.w, xc.x, xc.y, xc.z, xc.w};
    float wv0[8] = {wa0.x, wa0.y, wa0.z, wa0.w, wc0.x, wc0.y, wc0.z, wc0.w};
    float wv1[8] = {wa1.x, wa1.y, wa1.z, wa1.w, wc1.x, wc1.y, wc1.z, wc1.w};
    bf16x8 xhi, xlo, h0, l0, h1, l1;
#pragma unroll
    for (int i = 0; i < 8; i++) {
      unsigned short hh;
      hh = f2bf(xv[i]);  xhi[i] = (short)hh; xlo[i] = (short)f2bf(xv[i]  - bf2f(hh));
      hh = f2bf(wv0[i]); h0[i]  = (short)hh; l0[i]  = (short)f2bf(wv0[i] - bf2f(hh));
      hh = f2bf(wv1[i]); h1[i]  = (short)hh; l1[i]  = (short)f2bf(wv1[i] - bf2f(hh));
    }
    acc0 = __builtin_amdgcn_mfma_f32_16x16x32_bf16(xhi, h0, acc0, 0, 0, 0);
    acc0 = __builtin_amdgcn_mfma_f32_16x16x32_bf16(xlo, h0, acc0, 0, 0, 0);
    acc0 = __builtin_amdgcn_mfma_f32_16x16x32_bf16(xhi, l0, acc0, 0, 0, 0);
    acc0 = __builtin_amdgcn_mfma_f32_16x16x32_bf16(xlo, l0, acc0, 0, 0, 0);
    acc1 = __builtin_amdgcn_mfma_f32_16x16x32_bf16(xhi, h1, acc1, 0, 0, 0);
    acc1 = __builtin_amdgcn_mfma_f32_16x16x32_bf16(xlo, h1, acc1, 0, 0, 0);
    acc1 = __builtin_amdgcn_mfma_f32_16x16x32_bf16(xhi, l1, acc1, 0, 0, 0);
    acc1 = __builtin_amdgcn_mfma_f32_16x16x32_bf16(xlo, l1, acc1, 0, 0, 0);
  }
  *(f32x4*)&red[w][l][0] = acc0;
  *(f32x4*)&red[w][l][4] = acc1;
  __syncthreads();
  if (w == 0) {
    f32x4 s0 = {0.f,0.f,0.f,0.f}, s1 = {0.f,0.f,0.f,0.f};
#pragma unroll
    for (int ww = 0; ww < 4; ww++) {
      s0 += *(const f32x4*)&red[ww][l][0];
      s1 += *(const f32x4*)&red[ww][l][4];
    }
    float rb0 = rb[m], rb1 = rb[16 + m];
#pragma unroll
    for (int r = 0; r < 4; r++) {       // token row = kb*4+r
      float v0 = s0[r] + rb0;
      float v1 = s1[r] + rb1;
      float val = v0; int idx = m;
      if (v1 > v0) { val = v1; idx = 16 + m; }   // ties -> smaller e (np.argmax)
#pragma unroll
      for (int s = 1; s < 16; s <<= 1) {
        float ov = __shfl_xor(val, s);
        int oi = __shfl_xor(idx, s);
        if (ov > val || (ov == val && oi < idx)) { val = ov; idx = oi; }
      }
      if (m == 0) routed[b * 16 + kb * 4 + r] = idx;
    }
  }
}

// ---------------- K2: histogram + scan + XCD-pinned tile slots + scatter --------------
// meta[0..7] = tiles per XCD class; meta[8 + cls + 8*rank] = (e<<24)|(nrow<<16)|start.
// All tiles of expert e sit at consecutive ranks of class e&7 (L2 temporal locality).
__global__ __launch_bounds__(512) void scan_scatter_kernel(const int* __restrict__ routed,
    int* __restrict__ meta, int* __restrict__ order) {
  __shared__ int scnt[NEXP];
  __shared__ int scur[NEXP];
  int t = threadIdx.x;
  if (t < NEXP) scnt[t] = 0;
  __syncthreads();
  for (int n = t; n < N_TOK; n += 512) atomicAdd(&scnt[routed[n]], 1);
  __syncthreads();
  if (t < NEXP) {                           // lanes 0..31 of wave 0
    int c = scnt[t];
    int nt = (c + 31) >> 5;                 // 32-token tiles
    int ic = c;
#pragma unroll
    for (int s = 1; s < NEXP; s <<= 1) {
      int pc = __shfl_up(ic, s);
      if (t >= s) ic += pc;
    }
    int off = ic - c;
    scur[t] = off;
    int cls = t & 7, pos = t >> 3;          // XCD class, rank-in-class position
    int rank = 0;
#pragma unroll
    for (int j = 0; j < 4; j++) {
      int v = __shfl(nt, cls + j * 8);
      if (pos > j) rank += v;
    }
    for (int s2 = 0; s2 < nt; s2++) {
      int nr = c - s2 * 32; if (nr > 32) nr = 32;
      meta[8 + cls + 8 * (rank + s2)] = (t << 24) | (nr << 16) | (off + s2 * 32);
    }
    if (pos == 3) meta[cls] = rank + nt;    // per-class tile count
  }
  __syncthreads();
  for (int n = t; n < N_TOK; n += 512) {
    int e = routed[n];
    int p = atomicAdd(&scur[e], 1);         // intra-expert order arbitrary: out invariant
    order[p] = n;
  }
}

// ---------------- K3/K4: grouped GEMM with in-LDS transpose of fp32 weights ----------
// Tile 32 tok x COLS cols, THREADS = COLS*4 (4 or 8 waves, wave w owns 16 cols).
// Per 64-k chunk: stage A (gathered rows, fp32->bf16 for L1; NPASS passes of the
// proven 16-thr/row float4 pattern) and B (W[k][n] fp32 -> bf16 transposed, b128
// ds_write at exact bank floor) into swizzled LDS. Depth-2 register prefetch;
// vmcnt stays in flight across the barrier. 1-D grid, y-OUTERMOST in rank order.
template <int KDIM, int NTOT, int COLS, int THREADS, bool A_FP32, bool OUT_BF16>
__global__ __launch_bounds__(THREADS) void expert_gemm_kernel(
    const void* __restrict__ a_src, const float* __restrict__ wsrc,
    const float* __restrict__ bias, const int* __restrict__ meta,
    const int* __restrict__ order, void* __restrict__ outp) {
  constexpr int NCH = KDIM / 64;
  constexpr int NSLAB = NTOT / COLS;
  constexpr int NPASS = (32 * 16) / THREADS;  // A-staging passes: 512thr->1, 256thr->2
  __shared__ unsigned short AT[2][32 * 72];   //  9.2 KB
  __shared__ unsigned short BT[2][COLS * 72]; // 18.4 KB (64) / 36.9 KB (128)
  int bid = blockIdx.x, xcd = bid & 7, r = bid >> 3;
  int ntc = meta[xcd];
  if (r >= ntc * NSLAB) return;
  int y = r / ntc, rank = r - y * ntc;
  int info = meta[8 + xcd + 8 * rank];
  int e = info >> 24, nrow = (info >> 16) & 0xff, ts = info & 0xffff;
  int c0 = y * COLS;
  int t = threadIdx.x, w = t >> 6, l = t & 63, m = l & 15, kb = l >> 4;
  // staging roles: A = 32 rows x 64 kk (16 thr/row, float4/ushort4, NPASS passes);
  //                B = col bcn=t&(COLS-1), k-groups bkg=t/COLS and bkg+4 (8 k's each)
  int ak4 = (t & 15) * 4;
  int bcn = t & (COLS - 1), bkg = t / COLS;   // bkg in 0..3 for both shapes
  int atrp[NPASS];
  const float* aF[NPASS];
  const unsigned short* aH[NPASS];
#pragma unroll
  for (int pp = 0; pp < NPASS; pp++) {
    atrp[pp] = (t >> 4) + pp * (THREADS >> 4);
    int atok = order[ts + (atrp[pp] < nrow ? atrp[pp] : nrow - 1)];  // clamp: masked
    aF[pp] = (const float*)a_src + (size_t)atok * KDIM + ak4;
    aH[pp] = (const unsigned short*)a_src + (size_t)atok * KDIM + ak4;
  }
  const float* bS = wsrc + (size_t)e * KDIM * NTOT + c0 + bcn;

  float4 nAf[2][NPASS]; ushort4 nAh[2][NPASS];
  float nB[2][2][8];                          // all indices compile-time (full unroll)
  auto LOADC = [&](int c, int rbuf) {
#pragma unroll
    for (int pp = 0; pp < NPASS; pp++) {
      if constexpr (A_FP32) nAf[rbuf][pp] = *(const float4*)(aF[pp] + c * 64);
      else                  nAh[rbuf][pp] = *(const ushort4*)(aH[pp] + c * 64);
    }
#pragma unroll
    for (int u = 0; u < 2; u++)
#pragma unroll
      for (int j = 0; j < 8; j++)
        nB[rbuf][u][j] = bS[(size_t)(c * 64 + (bkg + 4 * u) * 8 + j) * NTOT];
  };

  f32x4 acc0 = {0.f,0.f,0.f,0.f}, acc1 = {0.f,0.f,0.f,0.f};
  LOADC(0, 0);
  LOADC(1, 1);
#pragma unroll
  for (int c = 0; c < NCH; c++) {
    const int p = c & 1;
#pragma unroll
    for (int pp = 0; pp < NPASS; pp++) {      // A writes b64: floor
      ushort4 av;
      if constexpr (A_FP32) {
        av.x = f2bf(nAf[p][pp].x); av.y = f2bf(nAf[p][pp].y);
        av.z = f2bf(nAf[p][pp].z); av.w = f2bf(nAf[p][pp].w);
      } else av = nAh[p][pp];
      *(ushort4*)&AT[p][swz(atrp[pp], ak4)] = av;
    }
#pragma unroll
    for (int u = 0; u < 2; u++) {             // B writes b128: exact bank floor
      bf16x8 pv;
#pragma unroll
      for (int j = 0; j < 8; j++) pv[j] = (short)f2bf(nB[p][u][j]);
      *(bf16x8*)&BT[p][swz(bcn, (bkg + 4 * u) * 8)] = pv;
    }
    if (c + 2 < NCH) LOADC(c + 2, p);         // WAR-safe: ds_writes read regs at issue
    asm volatile("s_waitcnt lgkmcnt(0)" ::: "memory");   // LDS writes visible
    __builtin_amdgcn_s_barrier();                        // vmcnt stays in flight
#pragma unroll
    for (int ks = 0; ks < 2; ks++) {
      int kk = ks * 32 + kb * 8;
      bf16x8 bfr = *(const bf16x8*)&BT[p][swz(w * 16 + m, kk)];
      bf16x8 a0  = *(const bf16x8*)&AT[p][swz(m, kk)];
      bf16x8 a1  = *(const bf16x8*)&AT[p][swz(16 + m, kk)];
      acc0 = __builtin_amdgcn_mfma_f32_16x16x32_bf16(a0, bfr, acc0, 0, 0, 0);
      acc1 = __builtin_amdgcn_mfma_f32_16x16x32_bf16(a1, bfr, acc1, 0, 0, 0);
    }
    // reads of buf p retire before next chunk's lgkmcnt(0)+barrier -> 1 barrier safe;
    // buf p is rewritten only at c+2, after that barrier.
  }
  int col = c0 + w * 16 + m;
  float bz = bias[e * NTOT + col];
#pragma unroll
  for (int r2 = 0; r2 < 4; r2++) {            // C/D: col=lane&15, row=kb*4+r (+16)
    int r0 = kb * 4 + r2;
    if (r0 < nrow) {
      int tok = order[ts + r0];
      float v = acc0[r2] + bz; v = v > 0.f ? v : 0.f;
      if constexpr (OUT_BF16)
        ((unsigned short*)outp)[(size_t)tok * NTOT + col] = f2bf(v);
      else
        ((float*)outp)[(size_t)tok * NTOT + col] = v;
    }
    int r1 = 16 + kb * 4 + r2;
    if (r1 < nrow) {
      int tok = order[ts + r1];
      float v = acc1[r2] + bz; v = v > 0.f ? v : 0.f;
      if constexpr (OUT_BF16)
        ((unsigned short*)outp)[(size_t)tok * NTOT + col] = f2bf(v);
      else
        ((float*)outp)[(size_t)tok * NTOT + col] = v;
    }
  }
}

// ---------------- launch ----------------

extern "C" void kernel_launch(void* const* d_in, const int* in_sizes, int n_in,
                              void* d_out, int out_size, void* d_ws, size_t ws_size,
                              hipStream_t stream) {
  const float* x  = (const float*)d_in[0];
  const float* rw = (const float*)d_in[1];
  const float* rb = (const float*)d_in[2];
  const float* w1 = (const float*)d_in[3];
  const float* b1 = (const float*)d_in[4];
  const float* w2 = (const float*)d_in[5];
  const float* b2 = (const float*)d_in[6];
  float* out = (float*)d_out;

  char* ws = (char*)d_ws;
  unsigned short* hb = (unsigned short*)(ws + 0);   // 2,097,152  h bf16 [N][H]
  int* routed = (int*)(ws + 2097152);               //    16,384
  int* order  = (int*)(ws + 2113536);               //    16,384
  int* meta   = (int*)(ws + 2129920);               //     4,608

  router_kernel<<<dim3(256), dim3(256), 0, stream>>>(x, rw, rb, routed);
  scan_scatter_kernel<<<dim3(1), dim3(512), 0, stream>>>(routed, meta, order);
  expert_gemm_kernel<DDIM, HDIM, 64, 256, true, true>
      <<<dim3(8 * TPX * (HDIM / 64)), dim3(256), 0, stream>>>(
      x, w1, b1, meta, order, hb);
  expert_gemm_kernel<HDIM, DDIM, 64, 256, false, false>
      <<<dim3(8 * TPX * (DDIM / 64)), dim3(256), 0, stream>>>(
      hb, w2, b2, meta, order, out);
}